// Round 6
// baseline (1807.160 us; speedup 1.0000x reference)
//
#include <hip/hip_runtime.h>

#define DD 128
#define PP 15
#define NNODES 10000
#define NEDGES 160000

typedef __attribute__((ext_vector_type(8))) short bf16x8;
typedef __attribute__((ext_vector_type(4))) float f32x4;

__device__ inline ushort f2bf(float f) {
  unsigned u = __builtin_bit_cast(unsigned, f);
  u += 0x7FFFu + ((u >> 16) & 1u);   // round-to-nearest-even
  return (ushort)(u >> 16);
}

__device__ inline float bf2f(ushort h) {
  unsigned u = ((unsigned)h) << 16;
  return __builtin_bit_cast(float, u);
}

// 2x f32 -> packed bf16 (RNE), single VALU op
__device__ inline uint cvt_pk(float lo, float hi) {
  uint r;
  asm("v_cvt_pk_bf16_f32 %0, %1, %2" : "=v"(r) : "v"(lo), "v"(hi));
  return r;
}

__device__ inline f32x4 mfma16(bf16x8 a, bf16x8 b, f32x4 c) {
  return __builtin_amdgcn_mfma_f32_16x16x32_bf16(a, b, c, 0, 0, 0);
}

// Pack ALL fp32 weights into bf16 MFMA B-fragment order, one launch.
__global__ __launch_bounds__(256) void pack_all(
    const float* __restrict__ ew0, const float* __restrict__ ew1,
    const float* __restrict__ ew2, const float* __restrict__ nw0,
    const float* __restrict__ nw1, const float* __restrict__ nw2,
    ushort* __restrict__ out) {
  int i = blockIdx.x * 256 + threadIdx.x;
  if (i >= 2211840) return;
  const float* w; int K; int j = i;
  if (i < 737280)       { w = ew0; K = 384; }
  else if (i < 983040)  { w = ew1; K = 128; j = i - 737280; }
  else if (i < 1228800) { w = ew2; K = 128; j = i - 983040; }
  else if (i < 1720320) { w = nw0; K = 256; j = i - 1228800; }
  else if (i < 1966080) { w = nw1; K = 128; j = i - 1720320; }
  else                  { w = nw2; K = 128; j = i - 1966080; }
  int per = K * 128;
  int p = j / per, q = j % per;
  int e = q & 7;
  int lane = (q >> 3) & 63;
  int t = q >> 9;
  int nkt = K >> 5;
  int kt = t % nkt, cb = t / nkt;
  int k = kt * 32 + ((lane >> 4) << 3) + e;
  int n = (cb << 4) + (lane & 15);
  out[i] = f2bf(w[(size_t)p * per + (size_t)k * 128 + n]);
}

// init edge bf16 stream + node fp32 working copy + node bf16 shadow, one launch
__global__ __launch_bounds__(256) void cvt_all(const float* __restrict__ ef,
                                               const float* __restrict__ nf,
                                               ushort* __restrict__ ebf,
                                               float* __restrict__ nbuf,
                                               ushort* __restrict__ nbf) {
  const int en4 = NEDGES * DD / 4;
  const int nn4 = NNODES * DD / 4;
  int i = blockIdx.x * 256 + threadIdx.x;
  if (i < en4) {
    float4 v = ((const float4*)ef)[i];
    ushort4 h;
    h.x = f2bf(v.x); h.y = f2bf(v.y); h.z = f2bf(v.z); h.w = f2bf(v.w);
    ((ushort4*)ebf)[i] = h;
  } else if (i < en4 + nn4) {
    int k = i - en4;
    float4 v = ((const float4*)nf)[k];
    ((float4*)nbuf)[k] = v;
    ushort4 h;
    h.x = f2bf(v.x); h.y = f2bf(v.y); h.z = f2bf(v.z); h.w = f2bf(v.w);
    ((ushort4*)nbf)[k] = h;
  }
}

// ---------------- CSR build: histogram + scan + scatter ----------------
__global__ __launch_bounds__(256) void hist_kernel(const int* __restrict__ dst,
                                                   int* __restrict__ cnt) {
  int i = blockIdx.x * 256 + threadIdx.x;
  if (i < NEDGES) atomicAdd(&cnt[dst[i]], 1);
}

__global__ __launch_bounds__(256) void scan_kernel(const int* __restrict__ cnt,
                                                   int* __restrict__ row_start,
                                                   int* __restrict__ cursor) {
  __shared__ int part[256];
  const int CH = (NNODES + 255) / 256;     // 40
  int t = threadIdx.x;
  int beg = t * CH, end = min(beg + CH, NNODES);
  int s = 0;
  for (int i = beg; i < end; ++i) s += cnt[i];
  part[t] = s;
  __syncthreads();
  for (int off = 1; off < 256; off <<= 1) {
    int v = (t >= off) ? part[t - off] : 0;
    __syncthreads();
    part[t] += v;
    __syncthreads();
  }
  int run = part[t] - s;     // exclusive prefix
  for (int i = beg; i < end; ++i) {
    row_start[i] = run;
    cursor[i] = run;
    run += cnt[i];
  }
  if (t == 255) row_start[NNODES] = NEDGES;
}

__global__ __launch_bounds__(256) void scatter_kernel(const int* __restrict__ dst,
                                                      int* __restrict__ cursor,
                                                      int* __restrict__ eidx) {
  int i = blockIdx.x * 256 + threadIdx.x;
  if (i < NEDGES) {
    int pos = atomicAdd(&cursor[dst[i]], 1);
    eidx[pos] = i;
  }
}

// ---------------- aggregation: one wave per node, bf16 edge rows ----------------
__global__ __launch_bounds__(256) void agg_kernel(const ushort* __restrict__ ebf,
                                                  ushort* __restrict__ abf,
                                                  const int* __restrict__ row_start,
                                                  const int* __restrict__ eidx) {
  int wv = threadIdx.x >> 6, lane = threadIdx.x & 63;
  int node = blockIdx.x * 4 + wv;
  if (node >= NNODES) return;
  int jb = row_start[node], je = row_start[node + 1];
  float ax = 0.f, ay = 0.f, bx = 0.f, by = 0.f;
  float cx = 0.f, cy = 0.f, dx = 0.f, dy = 0.f;
  int j = jb;
  for (; j + 3 < je; j += 4) {
    int e0 = eidx[j], e1 = eidx[j + 1], e2 = eidx[j + 2], e3 = eidx[j + 3];
    uint u0 = *(const uint*)(ebf + (size_t)e0 * DD + lane * 2);
    uint u1 = *(const uint*)(ebf + (size_t)e1 * DD + lane * 2);
    uint u2 = *(const uint*)(ebf + (size_t)e2 * DD + lane * 2);
    uint u3 = *(const uint*)(ebf + (size_t)e3 * DD + lane * 2);
    ax += bf2f((ushort)u0); ay += __builtin_bit_cast(float, u0 & 0xFFFF0000u);
    bx += bf2f((ushort)u1); by += __builtin_bit_cast(float, u1 & 0xFFFF0000u);
    cx += bf2f((ushort)u2); cy += __builtin_bit_cast(float, u2 & 0xFFFF0000u);
    dx += bf2f((ushort)u3); dy += __builtin_bit_cast(float, u3 & 0xFFFF0000u);
  }
  for (; j < je; ++j) {
    int e0 = eidx[j];
    uint u0 = *(const uint*)(ebf + (size_t)e0 * DD + lane * 2);
    ax += bf2f((ushort)u0); ay += __builtin_bit_cast(float, u0 & 0xFFFF0000u);
  }
  float sx = (ax + bx) + (cx + dx);
  float sy = (ay + by) + (cy + dy);
  *(uint*)&abf[(size_t)node * DD + lane * 2] = cvt_pk(sx, sy);
}

// ---------------- edge kernel: 64 edges x 128 out, 4 waves ----------------
// Single 48KB LDS tile S[64][384] = [src|dst|e]. Gathers staged ONCE and
// shared by all 4 waves (cuts L2 gather traffic 4x); weight fragments serve
// 64 rows (halves L2 weight traffic vs 32-row tiles). h1 overwrites the dead
// src region, h2 the dst region, e region survives for the residual.
__global__ __launch_bounds__(256) void edge_kernel(
    const ushort* __restrict__ nbf, ushort* __restrict__ ebf,
    const int* __restrict__ srcI, const int* __restrict__ dstI,
    const ushort* __restrict__ w0, const float* __restrict__ b0,
    const ushort* __restrict__ w1, const float* __restrict__ b1,
    const ushort* __restrict__ w2, const float* __restrict__ b2) {
  __shared__ ushort S[64 * 384];
  const int tid = threadIdx.x;
  const int e0 = blockIdx.x * 64;
  const int lane = tid & 63, wv = tid >> 6;
  const int l15 = lane & 15, l4 = lane >> 4;

  // stage cat = [n[src] | n[dst] | e] (bf16), 12 x 16B chunks per thread
#pragma unroll
  for (int i = 0; i < 12; ++i) {
    int c = i * 256 + tid;          // 0..3071
    int row = c / 48, f8 = c % 48;
    const ushort* sp;
    if (f8 < 16)       sp = nbf + (size_t)srcI[e0 + row] * DD + f8 * 8;
    else if (f8 < 32)  sp = nbf + (size_t)dstI[e0 + row] * DD + (f8 - 16) * 8;
    else               sp = ebf + (size_t)(e0 + row) * DD + (f8 - 32) * 8;
    bf16x8 v = *(const bf16x8*)sp;
    *(bf16x8*)&S[row * 384 + ((f8 ^ (row & 15)) * 8)] = v;
  }
  __syncthreads();

  const f32x4 z = {0.f, 0.f, 0.f, 0.f};
  const int cbA = wv * 2, cbB = wv * 2 + 1;
  f32x4 acc[4][2];

  // ---- GEMM1: [64x384] @ w0 ----
#pragma unroll
  for (int rb = 0; rb < 4; ++rb) { acc[rb][0] = z; acc[rb][1] = z; }
#pragma unroll
  for (int kt = 0; kt < 12; ++kt) {
    bf16x8 bA = *(const bf16x8*)(w0 + (size_t)((cbA * 12 + kt) * 64 + lane) * 8);
    bf16x8 bB = *(const bf16x8*)(w0 + (size_t)((cbB * 12 + kt) * 64 + lane) * 8);
#pragma unroll
    for (int rb = 0; rb < 4; ++rb) {
      int row = rb * 16 + l15;
      bf16x8 a = *(const bf16x8*)&S[row * 384 + (((kt * 4 + l4) ^ (row & 15)) * 8)];
      acc[rb][0] = mfma16(a, bA, acc[rb][0]);
      acc[rb][1] = mfma16(a, bB, acc[rb][1]);
    }
  }
  __syncthreads();   // all GEMM1 reads done before h1 overwrites src region

  // ep1: h1 = relu(acc + b0) -> chunks 0..15 (src region)
  {
    float biasA = b0[cbA * 16 + l15], biasB = b0[cbB * 16 + l15];
#pragma unroll
    for (int cbi = 0; cbi < 2; ++cbi) {
      int col = (wv * 2 + cbi) * 16 + l15;
      float bias = cbi ? biasB : biasA;
      int cs = col >> 3, c7 = col & 7;
#pragma unroll
      for (int rb = 0; rb < 4; ++rb) {
        float v0 = fmaxf(acc[rb][cbi][0] + bias, 0.f);
        float v1 = fmaxf(acc[rb][cbi][1] + bias, 0.f);
        float v2 = fmaxf(acc[rb][cbi][2] + bias, 0.f);
        float v3 = fmaxf(acc[rb][cbi][3] + bias, 0.f);
        uint p01 = cvt_pk(v0, v1), p23 = cvt_pk(v2, v3);
        int r0 = rb * 16 + l4 * 4;
        S[(r0 + 0) * 384 + ((cs ^ ((r0 + 0) & 15)) * 8) + c7] = (ushort)p01;
        S[(r0 + 1) * 384 + ((cs ^ ((r0 + 1) & 15)) * 8) + c7] = (ushort)(p01 >> 16);
        S[(r0 + 2) * 384 + ((cs ^ ((r0 + 2) & 15)) * 8) + c7] = (ushort)p23;
        S[(r0 + 3) * 384 + ((cs ^ ((r0 + 3) & 15)) * 8) + c7] = (ushort)(p23 >> 16);
      }
    }
  }
  __syncthreads();

  // ---- GEMM2: h1 @ w1 (A from chunks 0..15) ----
#pragma unroll
  for (int rb = 0; rb < 4; ++rb) { acc[rb][0] = z; acc[rb][1] = z; }
#pragma unroll
  for (int kt = 0; kt < 4; ++kt) {
    bf16x8 bA = *(const bf16x8*)(w1 + (size_t)((cbA * 4 + kt) * 64 + lane) * 8);
    bf16x8 bB = *(const bf16x8*)(w1 + (size_t)((cbB * 4 + kt) * 64 + lane) * 8);
#pragma unroll
    for (int rb = 0; rb < 4; ++rb) {
      int row = rb * 16 + l15;
      bf16x8 a = *(const bf16x8*)&S[row * 384 + (((kt * 4 + l4) ^ (row & 15)) * 8)];
      acc[rb][0] = mfma16(a, bA, acc[rb][0]);
      acc[rb][1] = mfma16(a, bB, acc[rb][1]);
    }
  }
  // ep2: h2 = relu(acc + b1) -> chunks 16..31 (dst region, dead after GEMM1;
  // disjoint from GEMM2's reads of 0..15, so no barrier before the writes)
  {
    float biasA = b1[cbA * 16 + l15], biasB = b1[cbB * 16 + l15];
#pragma unroll
    for (int cbi = 0; cbi < 2; ++cbi) {
      int col = (wv * 2 + cbi) * 16 + l15;
      float bias = cbi ? biasB : biasA;
      int cs = col >> 3, c7 = col & 7;
#pragma unroll
      for (int rb = 0; rb < 4; ++rb) {
        float v0 = fmaxf(acc[rb][cbi][0] + bias, 0.f);
        float v1 = fmaxf(acc[rb][cbi][1] + bias, 0.f);
        float v2 = fmaxf(acc[rb][cbi][2] + bias, 0.f);
        float v3 = fmaxf(acc[rb][cbi][3] + bias, 0.f);
        uint p01 = cvt_pk(v0, v1), p23 = cvt_pk(v2, v3);
        int r0 = rb * 16 + l4 * 4;
        S[(r0 + 0) * 384 + ((16 + (cs ^ ((r0 + 0) & 15))) * 8) + c7] = (ushort)p01;
        S[(r0 + 1) * 384 + ((16 + (cs ^ ((r0 + 1) & 15))) * 8) + c7] = (ushort)(p01 >> 16);
        S[(r0 + 2) * 384 + ((16 + (cs ^ ((r0 + 2) & 15))) * 8) + c7] = (ushort)p23;
        S[(r0 + 3) * 384 + ((16 + (cs ^ ((r0 + 3) & 15))) * 8) + c7] = (ushort)(p23 >> 16);
      }
    }
  }
  __syncthreads();

  // ---- GEMM3: h2 @ w2 (A from chunks 16..31) ----
#pragma unroll
  for (int rb = 0; rb < 4; ++rb) { acc[rb][0] = z; acc[rb][1] = z; }
#pragma unroll
  for (int kt = 0; kt < 4; ++kt) {
    bf16x8 bA = *(const bf16x8*)(w2 + (size_t)((cbA * 4 + kt) * 64 + lane) * 8);
    bf16x8 bB = *(const bf16x8*)(w2 + (size_t)((cbB * 4 + kt) * 64 + lane) * 8);
#pragma unroll
    for (int rb = 0; rb < 4; ++rb) {
      int row = rb * 16 + l15;
      bf16x8 a = *(const bf16x8*)&S[row * 384 + ((16 + ((kt * 4 + l4) ^ (row & 15))) * 8)];
      acc[rb][0] = mfma16(a, bA, acc[rb][0]);
      acc[rb][1] = mfma16(a, bB, acc[rb][1]);
    }
  }
  // final: res = e_in (chunks 32..47, intact) + acc + b2, written back in place.
  // Each (row,col) element read+written by exactly one thread -> no hazard.
  {
#pragma unroll
    for (int cbi = 0; cbi < 2; ++cbi) {
      int col = (wv * 2 + cbi) * 16 + l15;
      float bias = b2[col];
      int cs = col >> 3, c7 = col & 7;
#pragma unroll
      for (int rb = 0; rb < 4; ++rb) {
        int r0 = rb * 16 + l4 * 4;
        int i0 = (r0 + 0) * 384 + ((32 + (cs ^ ((r0 + 0) & 15))) * 8) + c7;
        int i1 = (r0 + 1) * 384 + ((32 + (cs ^ ((r0 + 1) & 15))) * 8) + c7;
        int i2 = (r0 + 2) * 384 + ((32 + (cs ^ ((r0 + 2) & 15))) * 8) + c7;
        int i3 = (r0 + 3) * 384 + ((32 + (cs ^ ((r0 + 3) & 15))) * 8) + c7;
        float v0 = bf2f(S[i0]) + acc[rb][cbi][0] + bias;
        float v1 = bf2f(S[i1]) + acc[rb][cbi][1] + bias;
        float v2 = bf2f(S[i2]) + acc[rb][cbi][2] + bias;
        float v3 = bf2f(S[i3]) + acc[rb][cbi][3] + bias;
        uint p01 = cvt_pk(v0, v1), p23 = cvt_pk(v2, v3);
        S[i0] = (ushort)p01;
        S[i1] = (ushort)(p01 >> 16);
        S[i2] = (ushort)p23;
        S[i3] = (ushort)(p23 >> 16);
      }
    }
  }
  __syncthreads();
  // coalesced write-out: 4 x 16B chunks per thread from the e region
#pragma unroll
  for (int i = 0; i < 4; ++i) {
    int c = i * 256 + tid;          // 0..1023
    int row = c >> 4, f8 = c & 15;
    bf16x8 v = *(const bf16x8*)&S[row * 384 + ((32 + (f8 ^ (row & 15))) * 8)];
    *(bf16x8*)&ebf[(size_t)(e0 + row) * DD + f8 * 8] = v;
  }
}

// ---------------- node kernel: 32 nodes x 128 out, 4 waves, fp32 residual ----------------
__global__ __launch_bounds__(256) void node_kernel(
    float* __restrict__ nbuf, ushort* __restrict__ nbf,
    const ushort* __restrict__ abf,
    const ushort* __restrict__ w0, const float* __restrict__ b0,
    const ushort* __restrict__ w1, const float* __restrict__ b1,
    const ushort* __restrict__ w2, const float* __restrict__ b2) {
  __shared__ ushort Alds[32 * 256];   // [n | agg]; chunks 16..31 reused as H2
  __shared__ ushort Hlds[32 * 128];
  const int tid = threadIdx.x;
  const int n0 = blockIdx.x * 32;
  const int lane = tid & 63, wv = tid >> 6;
  const int l15 = lane & 15, l4 = lane >> 4;

  // stage cat_n = [n | agg] (bf16), 4 chunks per thread
#pragma unroll
  for (int i = 0; i < 4; ++i) {
    int c = i * 256 + tid;          // 0..1023
    int row = c >> 5, f8 = c & 31;
    int node = n0 + row;
    bf16x8 v = {0, 0, 0, 0, 0, 0, 0, 0};
    if (node < NNODES) {
      const ushort* sp = (f8 < 16) ? nbf + (size_t)node * DD + f8 * 8
                                   : abf + (size_t)node * DD + (f8 - 16) * 8;
      v = *(const bf16x8*)sp;
    }
    *(bf16x8*)&Alds[row * 256 + ((f8 ^ (row & 15)) * 8)] = v;
  }
  __syncthreads();

  const f32x4 z = {0.f, 0.f, 0.f, 0.f};
  const int cbA = wv * 2, cbB = wv * 2 + 1;
  f32x4 acc[2][2];

  // ---- GEMM1: [32x256] @ nw0 ----
  acc[0][0] = z; acc[0][1] = z; acc[1][0] = z; acc[1][1] = z;
#pragma unroll
  for (int kt = 0; kt < 8; ++kt) {
    bf16x8 bA = *(const bf16x8*)(w0 + (size_t)((cbA * 8 + kt) * 64 + lane) * 8);
    bf16x8 bB = *(const bf16x8*)(w0 + (size_t)((cbB * 8 + kt) * 64 + lane) * 8);
    int sl = ((kt * 4 + l4) ^ l15) * 8;
    bf16x8 a0 = *(const bf16x8*)&Alds[l15 * 256 + sl];
    bf16x8 a1 = *(const bf16x8*)&Alds[(16 + l15) * 256 + sl];
    acc[0][0] = mfma16(a0, bA, acc[0][0]); acc[0][1] = mfma16(a0, bB, acc[0][1]);
    acc[1][0] = mfma16(a1, bA, acc[1][0]); acc[1][1] = mfma16(a1, bB, acc[1][1]);
  }
  {
    float biasA = b0[cbA * 16 + l15], biasB = b0[cbB * 16 + l15];
#pragma unroll
    for (int cbi = 0; cbi < 2; ++cbi) {
      int col = (wv * 2 + cbi) * 16 + l15;
      float bias = cbi ? biasB : biasA;
      int cs = col >> 3, c7 = col & 7;
#pragma unroll
      for (int rb = 0; rb < 2; ++rb) {
        float v0 = fmaxf(acc[rb][cbi][0] + bias, 0.f);
        float v1 = fmaxf(acc[rb][cbi][1] + bias, 0.f);
        float v2 = fmaxf(acc[rb][cbi][2] + bias, 0.f);
        float v3 = fmaxf(acc[rb][cbi][3] + bias, 0.f);
        uint p01 = cvt_pk(v0, v1), p23 = cvt_pk(v2, v3);
        int r0 = rb * 16 + l4 * 4;
        Hlds[(r0 + 0) * 128 + ((cs ^ ((r0 + 0) & 15)) * 8) + c7] = (ushort)p01;
        Hlds[(r0 + 1) * 128 + ((cs ^ ((r0 + 1) & 15)) * 8) + c7] = (ushort)(p01 >> 16);
        Hlds[(r0 + 2) * 128 + ((cs ^ ((r0 + 2) & 15)) * 8) + c7] = (ushort)p23;
        Hlds[(r0 + 3) * 128 + ((cs ^ ((r0 + 3) & 15)) * 8) + c7] = (ushort)(p23 >> 16);
      }
    }
  }
  __syncthreads();

  // ---- GEMM2 ----
  acc[0][0] = z; acc[0][1] = z; acc[1][0] = z; acc[1][1] = z;
#pragma unroll
  for (int kt = 0; kt < 4; ++kt) {
    bf16x8 bA = *(const bf16x8*)(w1 + (size_t)((cbA * 4 + kt) * 64 + lane) * 8);
    bf16x8 bB = *(const bf16x8*)(w1 + (size_t)((cbB * 4 + kt) * 64 + lane) * 8);
    int sl = ((kt * 4 + l4) ^ l15) * 8;
    bf16x8 a0 = *(const bf16x8*)&Hlds[l15 * 128 + sl];
    bf16x8 a1 = *(const bf16x8*)&Hlds[(16 + l15) * 128 + sl];
    acc[0][0] = mfma16(a0, bA, acc[0][0]); acc[0][1] = mfma16(a0, bB, acc[0][1]);
    acc[1][0] = mfma16(a1, bA, acc[1][0]); acc[1][1] = mfma16(a1, bB, acc[1][1]);
  }
  // ep2 -> Alds chunks 16..31 (agg region, dead after GEMM1)
  {
    float biasA = b1[cbA * 16 + l15], biasB = b1[cbB * 16 + l15];
#pragma unroll
    for (int cbi = 0; cbi < 2; ++cbi) {
      int col = (wv * 2 + cbi) * 16 + l15;
      float bias = cbi ? biasB : biasA;
      int cs = col >> 3, c7 = col & 7;
#pragma unroll
      for (int rb = 0; rb < 2; ++rb) {
        float v0 = fmaxf(acc[rb][cbi][0] + bias, 0.f);
        float v1 = fmaxf(acc[rb][cbi][1] + bias, 0.f);
        float v2 = fmaxf(acc[rb][cbi][2] + bias, 0.f);
        float v3 = fmaxf(acc[rb][cbi][3] + bias, 0.f);
        uint p01 = cvt_pk(v0, v1), p23 = cvt_pk(v2, v3);
        int r0 = rb * 16 + l4 * 4;
        Alds[(r0 + 0) * 256 + ((16 + (cs ^ ((r0 + 0) & 15))) * 8) + c7] = (ushort)p01;
        Alds[(r0 + 1) * 256 + ((16 + (cs ^ ((r0 + 1) & 15))) * 8) + c7] = (ushort)(p01 >> 16);
        Alds[(r0 + 2) * 256 + ((16 + (cs ^ ((r0 + 2) & 15))) * 8) + c7] = (ushort)p23;
        Alds[(r0 + 3) * 256 + ((16 + (cs ^ ((r0 + 3) & 15))) * 8) + c7] = (ushort)(p23 >> 16);
      }
    }
  }
  __syncthreads();

  // ---- GEMM3 + fp32 residual ----
  acc[0][0] = z; acc[0][1] = z; acc[1][0] = z; acc[1][1] = z;
#pragma unroll
  for (int kt = 0; kt < 4; ++kt) {
    bf16x8 bA = *(const bf16x8*)(w2 + (size_t)((cbA * 4 + kt) * 64 + lane) * 8);
    bf16x8 bB = *(const bf16x8*)(w2 + (size_t)((cbB * 4 + kt) * 64 + lane) * 8);
    int sl = (16 + ((kt * 4 + l4) ^ l15)) * 8;
    bf16x8 a0 = *(const bf16x8*)&Alds[l15 * 256 + sl];
    bf16x8 a1 = *(const bf16x8*)&Alds[(16 + l15) * 256 + sl];
    acc[0][0] = mfma16(a0, bA, acc[0][0]); acc[0][1] = mfma16(a0, bB, acc[0][1]);
    acc[1][0] = mfma16(a1, bA, acc[1][0]); acc[1][1] = mfma16(a1, bB, acc[1][1]);
  }
  {
#pragma unroll
    for (int cbi = 0; cbi < 2; ++cbi) {
      int col = (wv * 2 + cbi) * 16 + l15;
      float bias = b2[col];
#pragma unroll
      for (int rb = 0; rb < 2; ++rb) {
        int r0 = rb * 16 + l4 * 4;
        float res[4];
#pragma unroll
        for (int r = 0; r < 4; ++r) {
          int node = n0 + r0 + r;
          if (node < NNODES) {
            size_t off = (size_t)node * DD + col;
            res[r] = nbuf[off] + acc[rb][cbi][r] + bias;
            nbuf[off] = res[r];
          } else res[r] = 0.f;
        }
        uint p01 = cvt_pk(res[0], res[1]), p23 = cvt_pk(res[2], res[3]);
#pragma unroll
        for (int r = 0; r < 4; ++r) {
          int node = n0 + r0 + r;
          if (node < NNODES) {
            ushort h = (r == 0) ? (ushort)p01 : (r == 1) ? (ushort)(p01 >> 16)
                     : (r == 2) ? (ushort)p23 : (ushort)(p23 >> 16);
            nbf[(size_t)node * DD + col] = h;
          }
        }
      }
    }
  }
}

extern "C" void kernel_launch(void* const* d_in, const int* in_sizes, int n_in,
                              void* d_out, int out_size, void* d_ws, size_t ws_size,
                              hipStream_t stream) {
  const float* node_f = (const float*)d_in[0];
  const float* edge_f = (const float*)d_in[1];
  const int* srcI = (const int*)d_in[2];
  const int* dstI = (const int*)d_in[3];
  const float* ew0 = (const float*)d_in[4];
  const float* eb0 = (const float*)d_in[5];
  const float* ew1 = (const float*)d_in[6];
  const float* eb1 = (const float*)d_in[7];
  const float* ew2 = (const float*)d_in[8];
  const float* eb2 = (const float*)d_in[9];
  const float* nw0 = (const float*)d_in[10];
  const float* nb0 = (const float*)d_in[11];
  const float* nw1 = (const float*)d_in[12];
  const float* nb1 = (const float*)d_in[13];
  const float* nw2 = (const float*)d_in[14];
  const float* nb2 = (const float*)d_in[15];

  char* ws = (char*)d_ws;
  const size_t NB  = (size_t)NNODES * DD * 4;   //  5,120,000
  const size_t EBH = (size_t)NEDGES * DD * 2;   // 40,960,000
  const size_t NBH = (size_t)NNODES * DD * 2;   //  2,560,000
  ushort* ebf  = (ushort*)ws;
  float*  nbuf = (float*)(ws + EBH);
  ushort* nbf  = (ushort*)(ws + EBH + NB);
  ushort* abf  = (ushort*)(ws + EBH + NB + NBH);
  ushort* pw   = (ushort*)(ws + EBH + NB + 2 * NBH);
  ushort* pew0 = pw;                    // 15*384*128
  ushort* pew1 = pew0 + 737280;         // 15*128*128
  ushort* pew2 = pew1 + 245760;
  ushort* pnw0 = pew2 + 245760;         // 15*256*128
  ushort* pnw1 = pnw0 + 491520;
  ushort* pnw2 = pnw1 + 245760;
  const size_t WBYTES = 2211840ull * 2;  // total packed-weight bytes
  int* eidx      = (int*)(ws + EBH + NB + 2 * NBH + WBYTES);
  int* cnt       = eidx + NEDGES;
  int* row_start = cnt + NNODES;
  int* cursor    = row_start + NNODES + 1;

  // pack all weights (one launch)
  pack_all<<<(2211840 + 255) / 256, 256, 0, stream>>>(ew0, ew1, ew2, nw0, nw1,
                                                      nw2, pw);

  // CSR build (graph is static across layers)
  hipMemsetAsync(cnt, 0, NNODES * sizeof(int), stream);
  hist_kernel<<<(NEDGES + 255) / 256, 256, 0, stream>>>(dstI, cnt);
  scan_kernel<<<1, 256, 0, stream>>>(cnt, row_start, cursor);
  scatter_kernel<<<(NEDGES + 255) / 256, 256, 0, stream>>>(dstI, cursor, eidx);

  // init streams (one launch)
  {
    int tot = NEDGES * DD / 4 + NNODES * DD / 4;
    cvt_all<<<(tot + 255) / 256, 256, 0, stream>>>(edge_f, node_f, ebf, nbuf, nbf);
  }

  const int eblocks = NEDGES / 64;                 // 2500
  const int nblocks = (NNODES + 31) / 32;          // 313
  const int ablocks = (NNODES + 3) / 4;            // 2500

  for (int p = 0; p < PP; ++p) {
    edge_kernel<<<eblocks, 256, 0, stream>>>(
        nbf, ebf, srcI, dstI,
        pew0 + (size_t)p * 49152, eb0 + (size_t)p * DD,
        pew1 + (size_t)p * 16384, eb1 + (size_t)p * DD,
        pew2 + (size_t)p * 16384, eb2 + (size_t)p * DD);
    agg_kernel<<<ablocks, 256, 0, stream>>>(ebf, abf, row_start, eidx);
    node_kernel<<<nblocks, 256, 0, stream>>>(
        nbuf, nbf, abf,
        pnw0 + (size_t)p * 32768, nb0 + (size_t)p * DD,
        pnw1 + (size_t)p * 16384, nb1 + (size_t)p * DD,
        pnw2 + (size_t)p * 16384, nb2 + (size_t)p * DD);
  }

  hipMemcpyAsync(d_out, nbuf, NB, hipMemcpyDeviceToDevice, stream);
}

// Round 7
// 1341.685 us; speedup vs baseline: 1.3469x; 1.3469x over previous
//
#include <hip/hip_runtime.h>

#define DD 128
#define PP 15
#define NNODES 10000
#define NEDGES 160000

typedef __attribute__((ext_vector_type(8))) short bf16x8;
typedef __attribute__((ext_vector_type(4))) float f32x4;

__device__ inline ushort f2bf(float f) {
  unsigned u = __builtin_bit_cast(unsigned, f);
  u += 0x7FFFu + ((u >> 16) & 1u);   // round-to-nearest-even
  return (ushort)(u >> 16);
}

__device__ inline float bf2f(ushort h) {
  unsigned u = ((unsigned)h) << 16;
  return __builtin_bit_cast(float, u);
}

// 2x f32 -> packed bf16 (RNE), single VALU op
__device__ inline uint cvt_pk(float lo, float hi) {
  uint r;
  asm("v_cvt_pk_bf16_f32 %0, %1, %2" : "=v"(r) : "v"(lo), "v"(hi));
  return r;
}

__device__ inline f32x4 mfma16(bf16x8 a, bf16x8 b, f32x4 c) {
  return __builtin_amdgcn_mfma_f32_16x16x32_bf16(a, b, c, 0, 0, 0);
}

// Pack ALL fp32 weights into bf16 MFMA B-fragment order, one launch.
__global__ __launch_bounds__(256) void pack_all(
    const float* __restrict__ ew0, const float* __restrict__ ew1,
    const float* __restrict__ ew2, const float* __restrict__ nw0,
    const float* __restrict__ nw1, const float* __restrict__ nw2,
    ushort* __restrict__ out) {
  int i = blockIdx.x * 256 + threadIdx.x;
  if (i >= 2211840) return;
  const float* w; int K; int j = i;
  if (i < 737280)       { w = ew0; K = 384; }
  else if (i < 983040)  { w = ew1; K = 128; j = i - 737280; }
  else if (i < 1228800) { w = ew2; K = 128; j = i - 983040; }
  else if (i < 1720320) { w = nw0; K = 256; j = i - 1228800; }
  else if (i < 1966080) { w = nw1; K = 128; j = i - 1720320; }
  else                  { w = nw2; K = 128; j = i - 1966080; }
  int per = K * 128;
  int p = j / per, q = j % per;
  int e = q & 7;
  int lane = (q >> 3) & 63;
  int t = q >> 9;
  int nkt = K >> 5;
  int kt = t % nkt, cb = t / nkt;
  int k = kt * 32 + ((lane >> 4) << 3) + e;
  int n = (cb << 4) + (lane & 15);
  out[i] = f2bf(w[(size_t)p * per + (size_t)k * 128 + n]);
}

// init edge bf16 stream + node fp32 working copy + node bf16 shadow, one launch
__global__ __launch_bounds__(256) void cvt_all(const float* __restrict__ ef,
                                               const float* __restrict__ nf,
                                               ushort* __restrict__ ebf,
                                               float* __restrict__ nbuf,
                                               ushort* __restrict__ nbf) {
  const int en4 = NEDGES * DD / 4;
  const int nn4 = NNODES * DD / 4;
  int i = blockIdx.x * 256 + threadIdx.x;
  if (i < en4) {
    float4 v = ((const float4*)ef)[i];
    ushort4 h;
    h.x = f2bf(v.x); h.y = f2bf(v.y); h.z = f2bf(v.z); h.w = f2bf(v.w);
    ((ushort4*)ebf)[i] = h;
  } else if (i < en4 + nn4) {
    int k = i - en4;
    float4 v = ((const float4*)nf)[k];
    ((float4*)nbuf)[k] = v;
    ushort4 h;
    h.x = f2bf(v.x); h.y = f2bf(v.y); h.z = f2bf(v.z); h.w = f2bf(v.w);
    ((ushort4*)nbf)[k] = h;
  }
}

// ---------------- CSR build: histogram + scan + scatter ----------------
__global__ __launch_bounds__(256) void hist_kernel(const int* __restrict__ dst,
                                                   int* __restrict__ cnt) {
  int i = blockIdx.x * 256 + threadIdx.x;
  if (i < NEDGES) atomicAdd(&cnt[dst[i]], 1);
}

__global__ __launch_bounds__(256) void scan_kernel(const int* __restrict__ cnt,
                                                   int* __restrict__ row_start,
                                                   int* __restrict__ cursor) {
  __shared__ int part[256];
  const int CH = (NNODES + 255) / 256;     // 40
  int t = threadIdx.x;
  int beg = t * CH, end = min(beg + CH, NNODES);
  int s = 0;
  for (int i = beg; i < end; ++i) s += cnt[i];
  part[t] = s;
  __syncthreads();
  for (int off = 1; off < 256; off <<= 1) {
    int v = (t >= off) ? part[t - off] : 0;
    __syncthreads();
    part[t] += v;
    __syncthreads();
  }
  int run = part[t] - s;     // exclusive prefix
  for (int i = beg; i < end; ++i) {
    row_start[i] = run;
    cursor[i] = run;
    run += cnt[i];
  }
  if (t == 255) row_start[NNODES] = NEDGES;
}

__global__ __launch_bounds__(256) void scatter_kernel(const int* __restrict__ dst,
                                                      int* __restrict__ cursor,
                                                      int* __restrict__ eidx) {
  int i = blockIdx.x * 256 + threadIdx.x;
  if (i < NEDGES) {
    int pos = atomicAdd(&cursor[dst[i]], 1);
    eidx[pos] = i;
  }
}

// ---------------- aggregation: one wave per node, bf16 edge rows ----------------
__global__ __launch_bounds__(256) void agg_kernel(const ushort* __restrict__ ebf,
                                                  ushort* __restrict__ abf,
                                                  const int* __restrict__ row_start,
                                                  const int* __restrict__ eidx) {
  int wv = threadIdx.x >> 6, lane = threadIdx.x & 63;
  int node = blockIdx.x * 4 + wv;
  if (node >= NNODES) return;
  int jb = row_start[node], je = row_start[node + 1];
  float ax = 0.f, ay = 0.f, bx = 0.f, by = 0.f;
  float cx = 0.f, cy = 0.f, dx = 0.f, dy = 0.f;
  int j = jb;
  for (; j + 3 < je; j += 4) {
    int e0 = eidx[j], e1 = eidx[j + 1], e2 = eidx[j + 2], e3 = eidx[j + 3];
    uint u0 = *(const uint*)(ebf + (size_t)e0 * DD + lane * 2);
    uint u1 = *(const uint*)(ebf + (size_t)e1 * DD + lane * 2);
    uint u2 = *(const uint*)(ebf + (size_t)e2 * DD + lane * 2);
    uint u3 = *(const uint*)(ebf + (size_t)e3 * DD + lane * 2);
    ax += bf2f((ushort)u0); ay += __builtin_bit_cast(float, u0 & 0xFFFF0000u);
    bx += bf2f((ushort)u1); by += __builtin_bit_cast(float, u1 & 0xFFFF0000u);
    cx += bf2f((ushort)u2); cy += __builtin_bit_cast(float, u2 & 0xFFFF0000u);
    dx += bf2f((ushort)u3); dy += __builtin_bit_cast(float, u3 & 0xFFFF0000u);
  }
  for (; j < je; ++j) {
    int e0 = eidx[j];
    uint u0 = *(const uint*)(ebf + (size_t)e0 * DD + lane * 2);
    ax += bf2f((ushort)u0); ay += __builtin_bit_cast(float, u0 & 0xFFFF0000u);
  }
  float sx = (ax + bx) + (cx + dx);
  float sy = (ay + by) + (cy + dy);
  *(uint*)&abf[(size_t)node * DD + lane * 2] = cvt_pk(sx, sy);
}

// ---------------- edge kernel: 64 edges x 128 out, 8 waves (512 thr) ----------------
// One 16-col output slice per wave (cb = wv): weights read ONCE per block,
// per-wave phases are short (48/16/16 MFMA), acc = 16 VGPR, and 3 blocks/CU
// x 8 waves = 24 waves/CU for latency hiding. Single 48KB S tile: h1
// overwrites src region, h2 dst region, e region survives for the residual.
__global__ __launch_bounds__(512, 6) void edge_kernel(
    const ushort* __restrict__ nbf, ushort* __restrict__ ebf,
    const int* __restrict__ srcI, const int* __restrict__ dstI,
    const ushort* __restrict__ w0, const float* __restrict__ b0,
    const ushort* __restrict__ w1, const float* __restrict__ b1,
    const ushort* __restrict__ w2, const float* __restrict__ b2) {
  __shared__ ushort S[64 * 384];
  const int tid = threadIdx.x;
  const int e0 = blockIdx.x * 64;
  const int lane = tid & 63, wv = tid >> 6;   // wv = 0..7 = output col-block
  const int l15 = lane & 15, l4 = lane >> 4;

  // stage cat = [n[src] | n[dst] | e] (bf16), 6 x 16B chunks per thread
#pragma unroll
  for (int i = 0; i < 6; ++i) {
    int c = i * 512 + tid;          // 0..3071
    int row = c / 48, f8 = c % 48;
    const ushort* sp;
    if (f8 < 16)       sp = nbf + (size_t)srcI[e0 + row] * DD + f8 * 8;
    else if (f8 < 32)  sp = nbf + (size_t)dstI[e0 + row] * DD + (f8 - 16) * 8;
    else               sp = ebf + (size_t)(e0 + row) * DD + (f8 - 32) * 8;
    bf16x8 v = *(const bf16x8*)sp;
    *(bf16x8*)&S[row * 384 + ((f8 ^ (row & 15)) * 8)] = v;
  }
  __syncthreads();

  const f32x4 z = {0.f, 0.f, 0.f, 0.f};
  const int cb = wv;
  const int col = cb * 16 + l15;
  f32x4 acc[4];

  // ---- GEMM1: [64x384] @ w0 (one col-slice) ----
#pragma unroll
  for (int rb = 0; rb < 4; ++rb) acc[rb] = z;
#pragma unroll
  for (int kt = 0; kt < 12; ++kt) {
    bf16x8 bW = *(const bf16x8*)(w0 + (size_t)((cb * 12 + kt) * 64 + lane) * 8);
#pragma unroll
    for (int rb = 0; rb < 4; ++rb) {
      int row = rb * 16 + l15;
      bf16x8 a = *(const bf16x8*)&S[row * 384 + (((kt * 4 + l4) ^ (row & 15)) * 8)];
      acc[rb] = mfma16(a, bW, acc[rb]);
    }
  }
  __syncthreads();   // all GEMM1 reads done before h1 overwrites src region

  // ep1: h1 = relu(acc + b0) -> chunks 0..15 (src region)
  {
    float bias = b0[col];
    int cs = col >> 3, c7 = col & 7;
#pragma unroll
    for (int rb = 0; rb < 4; ++rb) {
      float v0 = fmaxf(acc[rb][0] + bias, 0.f);
      float v1 = fmaxf(acc[rb][1] + bias, 0.f);
      float v2 = fmaxf(acc[rb][2] + bias, 0.f);
      float v3 = fmaxf(acc[rb][3] + bias, 0.f);
      uint p01 = cvt_pk(v0, v1), p23 = cvt_pk(v2, v3);
      int r0 = rb * 16 + l4 * 4;
      S[(r0 + 0) * 384 + ((cs ^ ((r0 + 0) & 15)) * 8) + c7] = (ushort)p01;
      S[(r0 + 1) * 384 + ((cs ^ ((r0 + 1) & 15)) * 8) + c7] = (ushort)(p01 >> 16);
      S[(r0 + 2) * 384 + ((cs ^ ((r0 + 2) & 15)) * 8) + c7] = (ushort)p23;
      S[(r0 + 3) * 384 + ((cs ^ ((r0 + 3) & 15)) * 8) + c7] = (ushort)(p23 >> 16);
    }
  }
  __syncthreads();

  // ---- GEMM2: h1 @ w1 (A from chunks 0..15) ----
#pragma unroll
  for (int rb = 0; rb < 4; ++rb) acc[rb] = z;
#pragma unroll
  for (int kt = 0; kt < 4; ++kt) {
    bf16x8 bW = *(const bf16x8*)(w1 + (size_t)((cb * 4 + kt) * 64 + lane) * 8);
#pragma unroll
    for (int rb = 0; rb < 4; ++rb) {
      int row = rb * 16 + l15;
      bf16x8 a = *(const bf16x8*)&S[row * 384 + (((kt * 4 + l4) ^ (row & 15)) * 8)];
      acc[rb] = mfma16(a, bW, acc[rb]);
    }
  }
  // ep2: h2 = relu(acc + b1) -> chunks 16..31 (dst region; disjoint from
  // GEMM2's reads of chunks 0..15, so no barrier before these writes)
  {
    float bias = b1[col];
    int cs = col >> 3, c7 = col & 7;
#pragma unroll
    for (int rb = 0; rb < 4; ++rb) {
      float v0 = fmaxf(acc[rb][0] + bias, 0.f);
      float v1 = fmaxf(acc[rb][1] + bias, 0.f);
      float v2 = fmaxf(acc[rb][2] + bias, 0.f);
      float v3 = fmaxf(acc[rb][3] + bias, 0.f);
      uint p01 = cvt_pk(v0, v1), p23 = cvt_pk(v2, v3);
      int r0 = rb * 16 + l4 * 4;
      S[(r0 + 0) * 384 + ((16 + (cs ^ ((r0 + 0) & 15))) * 8) + c7] = (ushort)p01;
      S[(r0 + 1) * 384 + ((16 + (cs ^ ((r0 + 1) & 15))) * 8) + c7] = (ushort)(p01 >> 16);
      S[(r0 + 2) * 384 + ((16 + (cs ^ ((r0 + 2) & 15))) * 8) + c7] = (ushort)p23;
      S[(r0 + 3) * 384 + ((16 + (cs ^ ((r0 + 3) & 15))) * 8) + c7] = (ushort)(p23 >> 16);
    }
  }
  __syncthreads();

  // ---- GEMM3: h2 @ w2 (A from chunks 16..31) ----
#pragma unroll
  for (int rb = 0; rb < 4; ++rb) acc[rb] = z;
#pragma unroll
  for (int kt = 0; kt < 4; ++kt) {
    bf16x8 bW = *(const bf16x8*)(w2 + (size_t)((cb * 4 + kt) * 64 + lane) * 8);
#pragma unroll
    for (int rb = 0; rb < 4; ++rb) {
      int row = rb * 16 + l15;
      bf16x8 a = *(const bf16x8*)&S[row * 384 + ((16 + ((kt * 4 + l4) ^ (row & 15))) * 8)];
      acc[rb] = mfma16(a, bW, acc[rb]);
    }
  }
  // final: res = e_in (chunks 32..47, intact) + acc + b2, in place; each
  // (row,col) element is read+written by exactly one thread.
  {
    float bias = b2[col];
    int cs = col >> 3, c7 = col & 7;
#pragma unroll
    for (int rb = 0; rb < 4; ++rb) {
      int r0 = rb * 16 + l4 * 4;
      int i0 = (r0 + 0) * 384 + ((32 + (cs ^ ((r0 + 0) & 15))) * 8) + c7;
      int i1 = (r0 + 1) * 384 + ((32 + (cs ^ ((r0 + 1) & 15))) * 8) + c7;
      int i2 = (r0 + 2) * 384 + ((32 + (cs ^ ((r0 + 2) & 15))) * 8) + c7;
      int i3 = (r0 + 3) * 384 + ((32 + (cs ^ ((r0 + 3) & 15))) * 8) + c7;
      float v0 = bf2f(S[i0]) + acc[rb][0] + bias;
      float v1 = bf2f(S[i1]) + acc[rb][1] + bias;
      float v2 = bf2f(S[i2]) + acc[rb][2] + bias;
      float v3 = bf2f(S[i3]) + acc[rb][3] + bias;
      uint p01 = cvt_pk(v0, v1), p23 = cvt_pk(v2, v3);
      S[i0] = (ushort)p01;
      S[i1] = (ushort)(p01 >> 16);
      S[i2] = (ushort)p23;
      S[i3] = (ushort)(p23 >> 16);
    }
  }
  __syncthreads();
  // coalesced write-out: 2 x 16B chunks per thread from the e region
#pragma unroll
  for (int i = 0; i < 2; ++i) {
    int c = i * 512 + tid;          // 0..1023
    int row = c >> 4, f8 = c & 15;
    bf16x8 v = *(const bf16x8*)&S[row * 384 + ((32 + (f8 ^ (row & 15))) * 8)];
    *(bf16x8*)&ebf[(size_t)(e0 + row) * DD + f8 * 8] = v;
  }
}

// ---------------- node kernel: 32 nodes x 128 out, 4 waves, fp32 residual ----------------
__global__ __launch_bounds__(256) void node_kernel(
    float* __restrict__ nbuf, ushort* __restrict__ nbf,
    const ushort* __restrict__ abf,
    const ushort* __restrict__ w0, const float* __restrict__ b0,
    const ushort* __restrict__ w1, const float* __restrict__ b1,
    const ushort* __restrict__ w2, const float* __restrict__ b2) {
  __shared__ ushort Alds[32 * 256];   // [n | agg]; chunks 16..31 reused as H2
  __shared__ ushort Hlds[32 * 128];
  const int tid = threadIdx.x;
  const int n0 = blockIdx.x * 32;
  const int lane = tid & 63, wv = tid >> 6;
  const int l15 = lane & 15, l4 = lane >> 4;

  // stage cat_n = [n | agg] (bf16), 4 chunks per thread
#pragma unroll
  for (int i = 0; i < 4; ++i) {
    int c = i * 256 + tid;          // 0..1023
    int row = c >> 5, f8 = c & 31;
    int node = n0 + row;
    bf16x8 v = {0, 0, 0, 0, 0, 0, 0, 0};
    if (node < NNODES) {
      const ushort* sp = (f8 < 16) ? nbf + (size_t)node * DD + f8 * 8
                                   : abf + (size_t)node * DD + (f8 - 16) * 8;
      v = *(const bf16x8*)sp;
    }
    *(bf16x8*)&Alds[row * 256 + ((f8 ^ (row & 15)) * 8)] = v;
  }
  __syncthreads();

  const f32x4 z = {0.f, 0.f, 0.f, 0.f};
  const int cbA = wv * 2, cbB = wv * 2 + 1;
  f32x4 acc[2][2];

  // ---- GEMM1: [32x256] @ nw0 ----
  acc[0][0] = z; acc[0][1] = z; acc[1][0] = z; acc[1][1] = z;
#pragma unroll
  for (int kt = 0; kt < 8; ++kt) {
    bf16x8 bA = *(const bf16x8*)(w0 + (size_t)((cbA * 8 + kt) * 64 + lane) * 8);
    bf16x8 bB = *(const bf16x8*)(w0 + (size_t)((cbB * 8 + kt) * 64 + lane) * 8);
    int sl = ((kt * 4 + l4) ^ l15) * 8;
    bf16x8 a0 = *(const bf16x8*)&Alds[l15 * 256 + sl];
    bf16x8 a1 = *(const bf16x8*)&Alds[(16 + l15) * 256 + sl];
    acc[0][0] = mfma16(a0, bA, acc[0][0]); acc[0][1] = mfma16(a0, bB, acc[0][1]);
    acc[1][0] = mfma16(a1, bA, acc[1][0]); acc[1][1] = mfma16(a1, bB, acc[1][1]);
  }
  {
    float biasA = b0[cbA * 16 + l15], biasB = b0[cbB * 16 + l15];
#pragma unroll
    for (int cbi = 0; cbi < 2; ++cbi) {
      int col = (wv * 2 + cbi) * 16 + l15;
      float bias = cbi ? biasB : biasA;
      int cs = col >> 3, c7 = col & 7;
#pragma unroll
      for (int rb = 0; rb < 2; ++rb) {
        float v0 = fmaxf(acc[rb][cbi][0] + bias, 0.f);
        float v1 = fmaxf(acc[rb][cbi][1] + bias, 0.f);
        float v2 = fmaxf(acc[rb][cbi][2] + bias, 0.f);
        float v3 = fmaxf(acc[rb][cbi][3] + bias, 0.f);
        uint p01 = cvt_pk(v0, v1), p23 = cvt_pk(v2, v3);
        int r0 = rb * 16 + l4 * 4;
        Hlds[(r0 + 0) * 128 + ((cs ^ ((r0 + 0) & 15)) * 8) + c7] = (ushort)p01;
        Hlds[(r0 + 1) * 128 + ((cs ^ ((r0 + 1) & 15)) * 8) + c7] = (ushort)(p01 >> 16);
        Hlds[(r0 + 2) * 128 + ((cs ^ ((r0 + 2) & 15)) * 8) + c7] = (ushort)p23;
        Hlds[(r0 + 3) * 128 + ((cs ^ ((r0 + 3) & 15)) * 8) + c7] = (ushort)(p23 >> 16);
      }
    }
  }
  __syncthreads();

  // ---- GEMM2 ----
  acc[0][0] = z; acc[0][1] = z; acc[1][0] = z; acc[1][1] = z;
#pragma unroll
  for (int kt = 0; kt < 4; ++kt) {
    bf16x8 bA = *(const bf16x8*)(w1 + (size_t)((cbA * 4 + kt) * 64 + lane) * 8);
    bf16x8 bB = *(const bf16x8*)(w1 + (size_t)((cbB * 4 + kt) * 64 + lane) * 8);
    int sl = ((kt * 4 + l4) ^ l15) * 8;
    bf16x8 a0 = *(const bf16x8*)&Hlds[l15 * 128 + sl];
    bf16x8 a1 = *(const bf16x8*)&Hlds[(16 + l15) * 128 + sl];
    acc[0][0] = mfma16(a0, bA, acc[0][0]); acc[0][1] = mfma16(a0, bB, acc[0][1]);
    acc[1][0] = mfma16(a1, bA, acc[1][0]); acc[1][1] = mfma16(a1, bB, acc[1][1]);
  }
  // ep2 -> Alds chunks 16..31 (agg region, dead after GEMM1)
  {
    float biasA = b1[cbA * 16 + l15], biasB = b1[cbB * 16 + l15];
#pragma unroll
    for (int cbi = 0; cbi < 2; ++cbi) {
      int col = (wv * 2 + cbi) * 16 + l15;
      float bias = cbi ? biasB : biasA;
      int cs = col >> 3, c7 = col & 7;
#pragma unroll
      for (int rb = 0; rb < 2; ++rb) {
        float v0 = fmaxf(acc[rb][cbi][0] + bias, 0.f);
        float v1 = fmaxf(acc[rb][cbi][1] + bias, 0.f);
        float v2 = fmaxf(acc[rb][cbi][2] + bias, 0.f);
        float v3 = fmaxf(acc[rb][cbi][3] + bias, 0.f);
        uint p01 = cvt_pk(v0, v1), p23 = cvt_pk(v2, v3);
        int r0 = rb * 16 + l4 * 4;
        Alds[(r0 + 0) * 256 + ((16 + (cs ^ ((r0 + 0) & 15))) * 8) + c7] = (ushort)p01;
        Alds[(r0 + 1) * 256 + ((16 + (cs ^ ((r0 + 1) & 15))) * 8) + c7] = (ushort)(p01 >> 16);
        Alds[(r0 + 2) * 256 + ((16 + (cs ^ ((r0 + 2) & 15))) * 8) + c7] = (ushort)p23;
        Alds[(r0 + 3) * 256 + ((16 + (cs ^ ((r0 + 3) & 15))) * 8) + c7] = (ushort)(p23 >> 16);
      }
    }
  }
  __syncthreads();

  // ---- GEMM3 + fp32 residual ----
  acc[0][0] = z; acc[0][1] = z; acc[1][0] = z; acc[1][1] = z;
#pragma unroll
  for (int kt = 0; kt < 4; ++kt) {
    bf16x8 bA = *(const bf16x8*)(w2 + (size_t)((cbA * 4 + kt) * 64 + lane) * 8);
    bf16x8 bB = *(const bf16x8*)(w2 + (size_t)((cbB * 4 + kt) * 64 + lane) * 8);
    int sl = (16 + ((kt * 4 + l4) ^ l15)) * 8;
    bf16x8 a0 = *(const bf16x8*)&Alds[l15 * 256 + sl];
    bf16x8 a1 = *(const bf16x8*)&Alds[(16 + l15) * 256 + sl];
    acc[0][0] = mfma16(a0, bA, acc[0][0]); acc[0][1] = mfma16(a0, bB, acc[0][1]);
    acc[1][0] = mfma16(a1, bA, acc[1][0]); acc[1][1] = mfma16(a1, bB, acc[1][1]);
  }
  {
#pragma unroll
    for (int cbi = 0; cbi < 2; ++cbi) {
      int col = (wv * 2 + cbi) * 16 + l15;
      float bias = b2[col];
#pragma unroll
      for (int rb = 0; rb < 2; ++rb) {
        int r0 = rb * 16 + l4 * 4;
        float res[4];
#pragma unroll
        for (int r = 0; r < 4; ++r) {
          int node = n0 + r0 + r;
          if (node < NNODES) {
            size_t off = (size_t)node * DD + col;
            res[r] = nbuf[off] + acc[rb][cbi][r] + bias;
            nbuf[off] = res[r];
          } else res[r] = 0.f;
        }
        uint p01 = cvt_pk(res[0], res[1]), p23 = cvt_pk(res[2], res[3]);
#pragma unroll
        for (int r = 0; r < 4; ++r) {
          int node = n0 + r0 + r;
          if (node < NNODES) {
            ushort h = (r == 0) ? (ushort)p01 : (r == 1) ? (ushort)(p01 >> 16)
                     : (r == 2) ? (ushort)p23 : (ushort)(p23 >> 16);
            nbf[(size_t)node * DD + col] = h;
          }
        }
      }
    }
  }
}

extern "C" void kernel_launch(void* const* d_in, const int* in_sizes, int n_in,
                              void* d_out, int out_size, void* d_ws, size_t ws_size,
                              hipStream_t stream) {
  const float* node_f = (const float*)d_in[0];
  const float* edge_f = (const float*)d_in[1];
  const int* srcI = (const int*)d_in[2];
  const int* dstI = (const int*)d_in[3];
  const float* ew0 = (const float*)d_in[4];
  const float* eb0 = (const float*)d_in[5];
  const float* ew1 = (const float*)d_in[6];
  const float* eb1 = (const float*)d_in[7];
  const float* ew2 = (const float*)d_in[8];
  const float* eb2 = (const float*)d_in[9];
  const float* nw0 = (const float*)d_in[10];
  const float* nb0 = (const float*)d_in[11];
  const float* nw1 = (const float*)d_in[12];
  const float* nb1 = (const float*)d_in[13];
  const float* nw2 = (const float*)d_in[14];
  const float* nb2 = (const float*)d_in[15];

  char* ws = (char*)d_ws;
  const size_t NB  = (size_t)NNODES * DD * 4;   //  5,120,000
  const size_t EBH = (size_t)NEDGES * DD * 2;   // 40,960,000
  const size_t NBH = (size_t)NNODES * DD * 2;   //  2,560,000
  ushort* ebf  = (ushort*)ws;
  float*  nbuf = (float*)(ws + EBH);
  ushort* nbf  = (ushort*)(ws + EBH + NB);
  ushort* abf  = (ushort*)(ws + EBH + NB + NBH);
  ushort* pw   = (ushort*)(ws + EBH + NB + 2 * NBH);
  ushort* pew0 = pw;                    // 15*384*128
  ushort* pew1 = pew0 + 737280;         // 15*128*128
  ushort* pew2 = pew1 + 245760;
  ushort* pnw0 = pew2 + 245760;         // 15*256*128
  ushort* pnw1 = pnw0 + 491520;
  ushort* pnw2 = pnw1 + 245760;
  const size_t WBYTES = 2211840ull * 2;  // total packed-weight bytes
  int* eidx      = (int*)(ws + EBH + NB + 2 * NBH + WBYTES);
  int* cnt       = eidx + NEDGES;
  int* row_start = cnt + NNODES;
  int* cursor    = row_start + NNODES + 1;

  // pack all weights (one launch)
  pack_all<<<(2211840 + 255) / 256, 256, 0, stream>>>(ew0, ew1, ew2, nw0, nw1,
                                                      nw2, pw);

  // CSR build (graph is static across layers)
  hipMemsetAsync(cnt, 0, NNODES * sizeof(int), stream);
  hist_kernel<<<(NEDGES + 255) / 256, 256, 0, stream>>>(dstI, cnt);
  scan_kernel<<<1, 256, 0, stream>>>(cnt, row_start, cursor);
  scatter_kernel<<<(NEDGES + 255) / 256, 256, 0, stream>>>(dstI, cursor, eidx);

  // init streams (one launch)
  {
    int tot = NEDGES * DD / 4 + NNODES * DD / 4;
    cvt_all<<<(tot + 255) / 256, 256, 0, stream>>>(edge_f, node_f, ebf, nbuf, nbf);
  }

  const int eblocks = NEDGES / 64;                 // 2500
  const int nblocks = (NNODES + 31) / 32;          // 313
  const int ablocks = (NNODES + 3) / 4;            // 2500

  for (int p = 0; p < PP; ++p) {
    edge_kernel<<<eblocks, 512, 0, stream>>>(
        nbf, ebf, srcI, dstI,
        pew0 + (size_t)p * 49152, eb0 + (size_t)p * DD,
        pew1 + (size_t)p * 16384, eb1 + (size_t)p * DD,
        pew2 + (size_t)p * 16384, eb2 + (size_t)p * DD);
    agg_kernel<<<ablocks, 256, 0, stream>>>(ebf, abf, row_start, eidx);
    node_kernel<<<nblocks, 256, 0, stream>>>(
        nbuf, nbf, abf,
        pnw0 + (size_t)p * 32768, nb0 + (size_t)p * DD,
        pnw1 + (size_t)p * 16384, nb1 + (size_t)p * DD,
        pnw2 + (size_t)p * 16384, nb2 + (size_t)p * DD);
  }

  hipMemcpyAsync(d_out, nbuf, NB, hipMemcpyDeviceToDevice, stream);
}